// Round 17
// baseline (49.423 us; speedup 1.0000x reference)
//
#include <hip/hip_runtime.h>

typedef float v2f __attribute__((ext_vector_type(2)));
typedef short bf16x8 __attribute__((ext_vector_type(8)));
typedef float f32x4 __attribute__((ext_vector_type(4)));

namespace {
constexpr int B   = 8;
constexpr int TQ  = 256;
constexpr int TK  = 256;
constexpr int DQK = 512;
constexpr int DV  = 512;
constexpr int H   = 256;
constexpr int QB  = 4;           // q rows per attn block
constexpr float C2LOG2E   = 2.8853900817779268f;   // 2*log2(e)
constexpr float NEG2LOG2E = -2.8853900817779268f;
} // namespace

__device__ __forceinline__ uint32_t f2u(float x) { return __builtin_bit_cast(uint32_t, x); }
__device__ __forceinline__ float u2f(uint32_t x) { return __builtin_bit_cast(float, x); }
__device__ __forceinline__ uint32_t pack_hi(float x, float y) {
    return (f2u(y) & 0xFFFF0000u) | (f2u(x) >> 16);
}

// MFMA projections (bf16 hi/lo split), identical to R10..R16.
__global__ __launch_bounds__(256)
void proj_kernel(const float* __restrict__ Q, const float* __restrict__ Kin,
                 const float* __restrict__ Wq, const float* __restrict__ Wk,
                 float* __restrict__ qpc, float* __restrict__ kpc4)
{
    __shared__ short Ahi[4][64][8];
    __shared__ short Alo[4][64][8];
    __shared__ short Bhi[4][32][8];
    __shared__ short Blo[4][32][8];

    const bool kside = (blockIdx.z == 1);
    const float* A = kside ? Kin : Q;
    const float* W = kside ? Wk  : Wq;
    const int m0 = blockIdx.x * 64;
    const int n0 = blockIdx.y * 32;
    const int tid = threadIdx.x;

    const int am = tid >> 2, ag = tid & 3;
    const int bk = tid >> 3, bn4 = (tid & 7) * 4;
    const float4* aptr = (const float4*)(A + (m0 + am) * DQK) + ag * 2;
    const float*  wptr = W + bk * H + n0 + bn4;

    const int w = tid >> 6, l = tid & 63;
    const int wm = (w >> 1) * 32, wn = (w & 1) * 16;
    const int fg = l >> 4;
    const int fr = l & 15;

    float4 a0 = aptr[0], a1 = aptr[1];
    float4 bv = *(const float4*)wptr;

    f32x4 acc0 = {0.f, 0.f, 0.f, 0.f};
    f32x4 acc1 = {0.f, 0.f, 0.f, 0.f};

    for (int s = 0; s < 16; ++s) {
        __syncthreads();
        {
            float ah0 = u2f(f2u(a0.x) & 0xFFFF0000u), ah1 = u2f(f2u(a0.y) & 0xFFFF0000u);
            float ah2 = u2f(f2u(a0.z) & 0xFFFF0000u), ah3 = u2f(f2u(a0.w) & 0xFFFF0000u);
            float ah4 = u2f(f2u(a1.x) & 0xFFFF0000u), ah5 = u2f(f2u(a1.y) & 0xFFFF0000u);
            float ah6 = u2f(f2u(a1.z) & 0xFFFF0000u), ah7 = u2f(f2u(a1.w) & 0xFFFF0000u);
            int4 hw, lw;
            hw.x = (int)pack_hi(a0.x, a0.y); hw.y = (int)pack_hi(a0.z, a0.w);
            hw.z = (int)pack_hi(a1.x, a1.y); hw.w = (int)pack_hi(a1.z, a1.w);
            lw.x = (int)pack_hi(a0.x - ah0, a0.y - ah1);
            lw.y = (int)pack_hi(a0.z - ah2, a0.w - ah3);
            lw.z = (int)pack_hi(a1.x - ah4, a1.y - ah5);
            lw.w = (int)pack_hi(a1.z - ah6, a1.w - ah7);
            *(int4*)&Ahi[ag][am][0] = hw;
            *(int4*)&Alo[ag][am][0] = lw;
            const int g = bk >> 3, slot = bk & 7;
            float bb[4] = {bv.x, bv.y, bv.z, bv.w};
            #pragma unroll
            for (int i = 0; i < 4; ++i) {
                uint32_t u = f2u(bb[i]);
                float hf = u2f(u & 0xFFFF0000u);
                Bhi[g][bn4 + i][slot] = (short)(u >> 16);
                Blo[g][bn4 + i][slot] = (short)(f2u(bb[i] - hf) >> 16);
            }
        }
        __syncthreads();
        if (s < 15) {
            a0 = aptr[s * 8 + 8];
            a1 = aptr[s * 8 + 9];
            bv = *(const float4*)(wptr + (s + 1) * 32 * H);
        }
        bf16x8 ah_0 = *(const bf16x8*)&Ahi[fg][wm + fr][0];
        bf16x8 ah_1 = *(const bf16x8*)&Ahi[fg][wm + 16 + fr][0];
        bf16x8 al_0 = *(const bf16x8*)&Alo[fg][wm + fr][0];
        bf16x8 al_1 = *(const bf16x8*)&Alo[fg][wm + 16 + fr][0];
        bf16x8 bh   = *(const bf16x8*)&Bhi[fg][wn + fr][0];
        bf16x8 bl   = *(const bf16x8*)&Blo[fg][wn + fr][0];
        acc0 = __builtin_amdgcn_mfma_f32_16x16x32_bf16(ah_0, bh, acc0, 0, 0, 0);
        acc1 = __builtin_amdgcn_mfma_f32_16x16x32_bf16(ah_1, bh, acc1, 0, 0, 0);
        acc0 = __builtin_amdgcn_mfma_f32_16x16x32_bf16(ah_0, bl, acc0, 0, 0, 0);
        acc1 = __builtin_amdgcn_mfma_f32_16x16x32_bf16(ah_1, bl, acc1, 0, 0, 0);
        acc0 = __builtin_amdgcn_mfma_f32_16x16x32_bf16(al_0, bh, acc0, 0, 0, 0);
        acc1 = __builtin_amdgcn_mfma_f32_16x16x32_bf16(al_1, bh, acc1, 0, 0, 0);
    }

    const int col = n0 + wn + fr;
    #pragma unroll
    for (int mi = 0; mi < 2; ++mi) {
        f32x4 acc = mi ? acc1 : acc0;
        #pragma unroll
        for (int r = 0; r < 4; ++r) {
            const int row = m0 + wm + mi * 16 + fg * 4 + r;
            float val = __builtin_amdgcn_exp2f(acc[r] * C2LOG2E);
            if (!kside) {
                qpc[row * H + col] = val;
            } else {
                const int bb2 = row >> 8, kk = row & 255;
                kpc4[((bb2 * (H / 4) + (col >> 2)) * TK + kk) * 4 + (col & 3)] = val;
            }
        }
    }
}

// Fused scores + softmax + PV (R10 structure, 2-launch) with R14's PV fixes:
// p stored TRANSPOSED pT[kk][q]; PV = thread-per-column over FULL K (no accbuf
// round-trip, one fewer barrier); q-pair packed fma; kc prefetch in score.
// Block = (b, qgroup of 4), 512 threads, grid 512.
__global__ __launch_bounds__(512)
void attn_kernel(const float* __restrict__ qpc, const float* __restrict__ kpc4,
                 const float* __restrict__ wv, const float* __restrict__ values,
                 float* __restrict__ out)
{
    __shared__ float qlds[H][QB];        // 4 KB [h][q] (eq)
    __shared__ float wlds[H];            // 1 KB
    __shared__ float accbuf[4][QB][TK];  // 16 KB score partials
    __shared__ float pT[TK][QB];         // 4 KB p transposed
    __shared__ float rowsum[QB];

    const int b   = blockIdx.x >> 6;     // 64 q-groups per batch
    const int q0  = (blockIdx.x & 63) * QB;
    const int tid = threadIdx.x;

    for (int i = tid; i < QB * H; i += 512) {
        const int h = i >> 2, q = i & 3;
        qlds[h][q] = qpc[(b * TQ + q0 + q) * H + h];
    }
    if (tid < H) wlds[tid] = wv[tid];
    __syncthreads();

    // ---- score: 2 k-columns, 64 h per thread, pipelined kc loads ----
    {
        const int kp = tid & 127;            // k pair: 2kp, 2kp+1
        const int hg = tid >> 7;             // 0..3
        const int h0 = hg * 64;
        const float4* kc = (const float4*)kpc4 + (b * (H / 4) + (h0 >> 2)) * TK + 2 * kp;
        v2f a01a = {0.f, 0.f}, a23a = {0.f, 0.f};   // k even: q01, q23
        v2f a01b = {0.f, 0.f}, a23b = {0.f, 0.f};   // k odd
        const v2f one = {1.0f, 1.0f};
        float4 kva4 = kc[0];                 // prefetch h4 = 0
        float4 kvb4 = kc[1];
        #pragma unroll
        for (int h4 = 0; h4 < 16; ++h4) {
            float4 nkva, nkvb;
            if (h4 < 15) {                   // next h4's loads in flight
                nkva = kc[(h4 + 1) * TK];
                nkvb = kc[(h4 + 1) * TK + 1];
            }
            float4 w4 = *(const float4*)&wlds[h0 + h4 * 4];
            #pragma unroll
            for (int j = 0; j < 4; ++j) {
                const int h = h0 + h4 * 4 + j;
                const float ea = (j == 0) ? kva4.x : (j == 1) ? kva4.y : (j == 2) ? kva4.z : kva4.w;
                const float eb = (j == 0) ? kvb4.x : (j == 1) ? kvb4.y : (j == 2) ? kvb4.z : kvb4.w;
                const float wj = (j == 0) ? w4.x  : (j == 1) ? w4.y  : (j == 2) ? w4.z  : w4.w;
                float4 qa = *(const float4*)&qlds[h][0];   // broadcast eq (4 q)
                v2f q01 = {qa.x, qa.y}, q23 = {qa.z, qa.w};
                v2f ea2 = {ea, ea}, eb2 = {eb, eb}, w2 = {wj, wj};
                v2f d0a = __builtin_elementwise_fma(q01, ea2, one);  // eq*ek + 1
                v2f d1a = __builtin_elementwise_fma(q23, ea2, one);
                v2f d0b = __builtin_elementwise_fma(q01, eb2, one);
                v2f d1b = __builtin_elementwise_fma(q23, eb2, one);
                v2f r0a, r1a, r0b, r1b;
                r0a.x = __builtin_amdgcn_rcpf(d0a.x);
                r0a.y = __builtin_amdgcn_rcpf(d0a.y);
                r1a.x = __builtin_amdgcn_rcpf(d1a.x);
                r1a.y = __builtin_amdgcn_rcpf(d1a.y);
                r0b.x = __builtin_amdgcn_rcpf(d0b.x);
                r0b.y = __builtin_amdgcn_rcpf(d0b.y);
                r1b.x = __builtin_amdgcn_rcpf(d1b.x);
                r1b.y = __builtin_amdgcn_rcpf(d1b.y);
                a01a = __builtin_elementwise_fma(w2, r0a, a01a);
                a23a = __builtin_elementwise_fma(w2, r1a, a23a);
                a01b = __builtin_elementwise_fma(w2, r0b, a01b);
                a23b = __builtin_elementwise_fma(w2, r1b, a23b);
            }
            kva4 = nkva;
            kvb4 = nkvb;
        }
        accbuf[hg][0][2 * kp]     = a01a.x;
        accbuf[hg][1][2 * kp]     = a01a.y;
        accbuf[hg][2][2 * kp]     = a23a.x;
        accbuf[hg][3][2 * kp]     = a23a.y;
        accbuf[hg][0][2 * kp + 1] = a01b.x;
        accbuf[hg][1][2 * kp + 1] = a01b.y;
        accbuf[hg][2][2 * kp + 1] = a23b.x;
        accbuf[hg][3][2 * kp + 1] = a23b.y;
    }
    __syncthreads();

    // ---- combine 4 h-groups -> pT[kk][q] = exp2(-2log2e*acc) ----
    for (int i = tid; i < QB * TK; i += 512) {
        const int kk = i >> 2, q = i & 3;
        float s = (accbuf[0][q][kk] + accbuf[1][q][kk]) +
                  (accbuf[2][q][kk] + accbuf[3][q][kk]);
        pT[kk][q] = __builtin_amdgcn_exp2f(s * NEG2LOG2E);
    }
    __syncthreads();

    // ---- rowsum: wave w (0..3) reduces row q=w (waves 4-7 idle-compute) ----
    {
        const int q = (tid >> 6) & 3, lane = tid & 63;
        float s = (pT[lane][q] + pT[lane + 64][q]) +
                  (pT[lane + 128][q] + pT[lane + 192][q]);
        #pragma unroll
        for (int off = 1; off < 64; off <<= 1)
            s += __shfl_xor(s, off);
        if (tid < 256 && lane == 0) rowsum[q] = s;
    }
    // no barrier here: PV reads only pT (already synced); the barrier after
    // the PV loop orders rowsum[] writes before the normalize reads.

    // ---- PV: thread owns column c; full 256 k; q-pair packed ----
    {
        const int c = tid;
        const float* vb = values + b * TK * DV + c;
        v2f o01 = {0.f, 0.f}, o23 = {0.f, 0.f};
        #pragma unroll 8
        for (int kk = 0; kk < TK; ++kk) {
            float v = vb[kk * DV];
            float4 p4 = *(const float4*)&pT[kk][0];   // broadcast b128
            v2f vv = {v, v};
            o01 = __builtin_elementwise_fma((v2f){p4.x, p4.y}, vv, o01);
            o23 = __builtin_elementwise_fma((v2f){p4.z, p4.w}, vv, o23);
        }
        __syncthreads();   // rowsum[] visible to all
        float* ob = out + (b * TQ + q0) * DV + c;
        ob[0 * DV] = o01.x * __builtin_amdgcn_rcpf(rowsum[0]);
        ob[1 * DV] = o01.y * __builtin_amdgcn_rcpf(rowsum[1]);
        ob[2 * DV] = o23.x * __builtin_amdgcn_rcpf(rowsum[2]);
        ob[3 * DV] = o23.y * __builtin_amdgcn_rcpf(rowsum[3]);
    }
}

extern "C" void kernel_launch(void* const* d_in, const int* in_sizes, int n_in,
                              void* d_out, int out_size, void* d_ws, size_t ws_size,
                              hipStream_t stream)
{
    const float* queries = (const float*)d_in[0];
    const float* keys    = (const float*)d_in[1];
    const float* values  = (const float*)d_in[2];
    const float* Wq      = (const float*)d_in[3];
    const float* Wk      = (const float*)d_in[4];
    const float* wv      = (const float*)d_in[5];
    float* out  = (float*)d_out;
    float* qpc  = (float*)d_ws;                    // (B*TQ, H)        2 MB (exp'd)
    float* kpc4 = qpc + B * TQ * H;                // (B, H/4, TK, 4)  2 MB (exp'd)

    dim3 gproj(B * TQ / 64, H / 32, 2);
    proj_kernel<<<gproj, 256, 0, stream>>>(queries, keys, Wq, Wk, qpc, kpc4);
    attn_kernel<<<B * (TQ / QB), 512, 0, stream>>>(qpc, kpc4, wv, values, out);
}